// Round 1
// baseline (664.431 us; speedup 1.0000x reference)
//
#include <hip/hip_runtime.h>
#include <hip/hip_bf16.h>

// Problem constants
constexpr int Bn = 8, Sn = 2048, En = 512, Hn = 4, Dn = 128;
constexpr int BHn = Bn * Hn;          // 32
constexpr int Mqkv = Bn * Sn;         // 16384

typedef __attribute__((ext_vector_type(8))) short short8;
typedef __attribute__((ext_vector_type(4))) float f32x4;

__device__ __forceinline__ unsigned short f2bf(float f) {
  unsigned int u = __builtin_bit_cast(unsigned int, f);
  u += 0x7FFF + ((u >> 16) & 1);   // round-to-nearest-even
  return (unsigned short)(u >> 16);
}

// ---------------------------------------------------------------------------
// K1: QKV projection.  out[z][bh][s][d] (bf16) = x[b,s,:]@W[:,e] + bias[s]
// grid (M/128, N/128=4, 3); block 256 (4 waves, each 64x64 of the 128x128 tile)
// ---------------------------------------------------------------------------
__global__ __launch_bounds__(256) void qkv_kernel(
    const float* __restrict__ x, const float* __restrict__ Wq,
    const float* __restrict__ Wk, const float* __restrict__ Wv,
    const float* __restrict__ bq, const float* __restrict__ bk,
    const float* __restrict__ bv, unsigned short* __restrict__ qkv) {
  const int z = blockIdx.z;
  const float* W = (z == 0) ? Wq : (z == 1 ? Wk : Wv);
  const float* bias = (z == 0) ? bq : (z == 1 ? bk : bv);
  unsigned short* out = qkv + (size_t)z * BHn * Sn * Dn;

  __shared__ unsigned short As[128][40];   // [m][k], pad to 40
  __shared__ unsigned short BsT[128][40];  // [n][k] (W transposed)

  const int t = threadIdx.x;
  const int l = t & 63, w = t >> 6;
  const int wm = w >> 1, wn = w & 1;
  const int m0 = blockIdx.x * 128, n0 = blockIdx.y * 128;

  f32x4 acc[4][4] = {};

  for (int k0 = 0; k0 < En; k0 += 32) {
    __syncthreads();
    // stage A: x[m0:m0+128, k0:k0+32] -> bf16
#pragma unroll
    for (int i = 0; i < 4; ++i) {
      int idx = t + i * 256;
      int row = idx >> 3, c4 = (idx & 7) * 4;
      float4 v = *reinterpret_cast<const float4*>(&x[(size_t)(m0 + row) * En + k0 + c4]);
      ushort4 p;
      p.x = f2bf(v.x); p.y = f2bf(v.y); p.z = f2bf(v.z); p.w = f2bf(v.w);
      *reinterpret_cast<ushort4*>(&As[row][c4]) = p;
    }
    // stage B^T: W[k0:k0+32, n0:n0+128] -> BsT[n][k]
#pragma unroll
    for (int i = 0; i < 4; ++i) {
      int idx = t + i * 256;
      int kk = idx >> 5, c4 = (idx & 31) * 4;
      float4 v = *reinterpret_cast<const float4*>(&W[(size_t)(k0 + kk) * En + n0 + c4]);
      BsT[c4 + 0][kk] = f2bf(v.x);
      BsT[c4 + 1][kk] = f2bf(v.y);
      BsT[c4 + 2][kk] = f2bf(v.z);
      BsT[c4 + 3][kk] = f2bf(v.w);
    }
    __syncthreads();

    const int koff = (l >> 4) * 8;
    short8 a[4], bfr[4];
#pragma unroll
    for (int m = 0; m < 4; ++m)
      a[m] = *reinterpret_cast<const short8*>(&As[wm * 64 + m * 16 + (l & 15)][koff]);
#pragma unroll
    for (int n = 0; n < 4; ++n)
      bfr[n] = *reinterpret_cast<const short8*>(&BsT[wn * 64 + n * 16 + (l & 15)][koff]);
#pragma unroll
    for (int m = 0; m < 4; ++m)
#pragma unroll
      for (int n = 0; n < 4; ++n)
        acc[m][n] = __builtin_amdgcn_mfma_f32_16x16x32_bf16(a[m], bfr[n], acc[m][n], 0, 0, 0);
  }

#pragma unroll
  for (int m = 0; m < 4; ++m)
#pragma unroll
    for (int n = 0; n < 4; ++n)
#pragma unroll
      for (int j = 0; j < 4; ++j) {
        int row = m0 + wm * 64 + m * 16 + (l >> 4) * 4 + j;
        int col = n0 + wn * 64 + n * 16 + (l & 15);
        int s = row & (Sn - 1);
        float v = acc[m][n][j] + bias[s];
        int b = row >> 11;           // row / 2048
        int h = col >> 7, d = col & 127;
        out[(size_t)((b * Hn + h) * Sn + s) * Dn + d] = f2bf(v);
      }
}

// ---------------------------------------------------------------------------
// K2: scores = scale * q @ k^T  -> raw f32 into attn region of d_out
// grid (S/128, S/128, BH); block 256
// ---------------------------------------------------------------------------
__global__ __launch_bounds__(256) void scores_kernel(
    const unsigned short* __restrict__ qkv, float* __restrict__ attn) {
  const int bh = blockIdx.z;
  const unsigned short* q = qkv + (size_t)bh * Sn * Dn;
  const unsigned short* k = qkv + (size_t)BHn * Sn * Dn + (size_t)bh * Sn * Dn;

  __shared__ unsigned short Qs[128][136];
  __shared__ unsigned short Ks[128][136];

  const int t = threadIdx.x, l = t & 63, w = t >> 6;
  const int wm = w >> 1, wn = w & 1;
  const int s0 = blockIdx.x * 128, t0 = blockIdx.y * 128;

#pragma unroll
  for (int i = 0; i < 8; ++i) {
    int idx = t + i * 256;
    int row = idx >> 4, c8 = (idx & 15) * 8;
    *reinterpret_cast<short8*>(&Qs[row][c8]) =
        *reinterpret_cast<const short8*>(&q[(size_t)(s0 + row) * Dn + c8]);
    *reinterpret_cast<short8*>(&Ks[row][c8]) =
        *reinterpret_cast<const short8*>(&k[(size_t)(t0 + row) * Dn + c8]);
  }
  __syncthreads();

  f32x4 acc[4][4] = {};
#pragma unroll
  for (int ks = 0; ks < Dn; ks += 32) {
    const int koff = ks + (l >> 4) * 8;
    short8 a[4], bfr[4];
#pragma unroll
    for (int m = 0; m < 4; ++m)
      a[m] = *reinterpret_cast<const short8*>(&Qs[wm * 64 + m * 16 + (l & 15)][koff]);
#pragma unroll
    for (int n = 0; n < 4; ++n)
      bfr[n] = *reinterpret_cast<const short8*>(&Ks[wn * 64 + n * 16 + (l & 15)][koff]);
#pragma unroll
    for (int m = 0; m < 4; ++m)
#pragma unroll
      for (int n = 0; n < 4; ++n)
        acc[m][n] = __builtin_amdgcn_mfma_f32_16x16x32_bf16(a[m], bfr[n], acc[m][n], 0, 0, 0);
  }

  const float scale = 0.022097086912079608f;  // 1/sqrt(2048)
  float* outp = attn + (size_t)bh * Sn * Sn;
#pragma unroll
  for (int m = 0; m < 4; ++m)
#pragma unroll
    for (int n = 0; n < 4; ++n)
#pragma unroll
      for (int j = 0; j < 4; ++j) {
        int row = s0 + wm * 64 + m * 16 + (l >> 4) * 4 + j;
        int col = t0 + wn * 64 + n * 16 + (l & 15);
        outp[(size_t)row * Sn + col] = acc[m][n][j] * scale;
      }
}

// ---------------------------------------------------------------------------
// K3: in-place row softmax + ⊙ Wepi.  one block per attn row (65536 rows)
// ---------------------------------------------------------------------------
__global__ __launch_bounds__(256) void softmax_kernel(
    float* __restrict__ attn, const float* __restrict__ Wepi) {
  const size_t r = blockIdx.x;
  const int s = (int)(r & (Sn - 1));
  float* row = attn + r * Sn;
  const float* wrow = Wepi + (size_t)s * Sn;
  const int t = threadIdx.x, l = t & 63, w = t >> 6;

  float4 v0 = *reinterpret_cast<const float4*>(&row[t * 4]);
  float4 v1 = *reinterpret_cast<const float4*>(&row[1024 + t * 4]);
  float vals[8] = {v0.x, v0.y, v0.z, v0.w, v1.x, v1.y, v1.z, v1.w};

  float m = vals[0];
#pragma unroll
  for (int j = 1; j < 8; ++j) m = fmaxf(m, vals[j]);
  for (int off = 32; off; off >>= 1) m = fmaxf(m, __shfl_xor(m, off));
  __shared__ float red[8];
  if (l == 0) red[w] = m;
  __syncthreads();
  m = fmaxf(fmaxf(red[0], red[1]), fmaxf(red[2], red[3]));

  float sum = 0.f;
#pragma unroll
  for (int j = 0; j < 8; ++j) {
    vals[j] = __expf(vals[j] - m);
    sum += vals[j];
  }
  for (int off = 32; off; off >>= 1) sum += __shfl_xor(sum, off);
  if (l == 0) red[4 + w] = sum;
  __syncthreads();
  sum = red[4] + red[5] + red[6] + red[7];
  const float inv = 1.0f / sum;

  float4 w0 = *reinterpret_cast<const float4*>(&wrow[t * 4]);
  float4 w1 = *reinterpret_cast<const float4*>(&wrow[1024 + t * 4]);
  float4 o0, o1;
  o0.x = vals[0] * inv * w0.x; o0.y = vals[1] * inv * w0.y;
  o0.z = vals[2] * inv * w0.z; o0.w = vals[3] * inv * w0.w;
  o1.x = vals[4] * inv * w1.x; o1.y = vals[5] * inv * w1.y;
  o1.z = vals[6] * inv * w1.z; o1.w = vals[7] * inv * w1.w;
  *reinterpret_cast<float4*>(&row[t * 4]) = o0;
  *reinterpret_cast<float4*>(&row[1024 + t * 4]) = o1;
}

// ---------------------------------------------------------------------------
// K4: effect = attn @ v + bo.  grid (S/128, 1, BH); block 256
// ---------------------------------------------------------------------------
__global__ __launch_bounds__(256) void pv_kernel(
    const float* __restrict__ attn, const unsigned short* __restrict__ qkv,
    const float* __restrict__ bo, float* __restrict__ effect) {
  const int bh = blockIdx.z;
  const unsigned short* v = qkv + (size_t)2 * BHn * Sn * Dn + (size_t)bh * Sn * Dn;
  const float* arow = attn + (size_t)bh * Sn * Sn;

  __shared__ unsigned short As[128][40];   // attn chunk [s][t] bf16
  __shared__ unsigned short VsT[128][40];  // v transposed [d][t]

  const int t = threadIdx.x, l = t & 63, w = t >> 6;
  const int wm = w >> 1, wn = w & 1;
  const int s0 = blockIdx.x * 128;

  f32x4 acc[4][4] = {};
  for (int k0 = 0; k0 < Sn; k0 += 32) {
    __syncthreads();
#pragma unroll
    for (int i = 0; i < 4; ++i) {
      int idx = t + i * 256;
      int row = idx >> 3, c4 = (idx & 7) * 4;
      float4 a4 = *reinterpret_cast<const float4*>(&arow[(size_t)(s0 + row) * Sn + k0 + c4]);
      ushort4 p;
      p.x = f2bf(a4.x); p.y = f2bf(a4.y); p.z = f2bf(a4.z); p.w = f2bf(a4.w);
      *reinterpret_cast<ushort4*>(&As[row][c4]) = p;
    }
#pragma unroll
    for (int i = 0; i < 2; ++i) {
      int idx = t + i * 256;
      int tt = idx >> 4, c8 = (idx & 15) * 8;
      short8 vv = *reinterpret_cast<const short8*>(&v[(size_t)(k0 + tt) * Dn + c8]);
#pragma unroll
      for (int j = 0; j < 8; ++j) VsT[c8 + j][tt] = (unsigned short)vv[j];
    }
    __syncthreads();

    const int koff = (l >> 4) * 8;
    short8 a[4], bfr[4];
#pragma unroll
    for (int m = 0; m < 4; ++m)
      a[m] = *reinterpret_cast<const short8*>(&As[wm * 64 + m * 16 + (l & 15)][koff]);
#pragma unroll
    for (int n = 0; n < 4; ++n)
      bfr[n] = *reinterpret_cast<const short8*>(&VsT[wn * 64 + n * 16 + (l & 15)][koff]);
#pragma unroll
    for (int m = 0; m < 4; ++m)
#pragma unroll
      for (int n = 0; n < 4; ++n)
        acc[m][n] = __builtin_amdgcn_mfma_f32_16x16x32_bf16(a[m], bfr[n], acc[m][n], 0, 0, 0);
  }

  const int b = bh >> 2, h = bh & 3;
#pragma unroll
  for (int m = 0; m < 4; ++m)
#pragma unroll
    for (int n = 0; n < 4; ++n)
#pragma unroll
      for (int j = 0; j < 4; ++j) {
        int srow = s0 + wm * 64 + m * 16 + (l >> 4) * 4 + j;
        int dcol = wn * 64 + n * 16 + (l & 15);
        effect[(size_t)(b * Sn + srow) * En + h * Dn + dcol] = acc[m][n][j] + bo[srow];
      }
}

// ---------------------------------------------------------------------------
extern "C" void kernel_launch(void* const* d_in, const int* in_sizes, int n_in,
                              void* d_out, int out_size, void* d_ws, size_t ws_size,
                              hipStream_t stream) {
  const float* x    = (const float*)d_in[0];
  const float* Wq   = (const float*)d_in[1];
  const float* Wk   = (const float*)d_in[2];
  const float* Wv   = (const float*)d_in[3];
  const float* Wepi = (const float*)d_in[4];
  const float* bq   = (const float*)d_in[5];
  const float* bk   = (const float*)d_in[6];
  const float* bv   = (const float*)d_in[7];
  const float* bo   = (const float*)d_in[8];

  float* effect = (float*)d_out;
  float* attn = effect + (size_t)Bn * Sn * En;   // attn region of d_out
  unsigned short* qkv = (unsigned short*)d_ws;   // q|k|v bf16, 3 * 16.78 MB

  qkv_kernel<<<dim3(Mqkv / 128, En / 128, 3), 256, 0, stream>>>(x, Wq, Wk, Wv, bq, bk, bv, qkv);
  scores_kernel<<<dim3(Sn / 128, Sn / 128, BHn), 256, 0, stream>>>(qkv, attn);
  softmax_kernel<<<dim3(BHn * Sn), 256, 0, stream>>>(attn, Wepi);
  pv_kernel<<<dim3(Sn / 128, 1, BHn), 256, 0, stream>>>(attn, qkv, bo, effect);
}